// Round 1
// baseline (454.602 us; speedup 1.0000x reference)
//
#include <hip/hip_runtime.h>

// AdjacencyMatrix == 4 chained GEMVs with W^T + diagonal scale:
//   v1 = W[0:1024,:]^T x ; v2 = W^T v1 ; v3 = W^T v2 ;
//   v4[last256] = (W^T v3)[last256] ; out[t] = W[j,j]*v4[j], j=7936+t.
//
// Cross-round model (R1..R5): dur_us = kernels + ~265 us FIXED harness
// overhead in the timed window (1 GiB ws poison fill @160us + 256 MiB W
// restore @~85us + launch). Kernels ~180 us vs ~105 us traffic roofline.
//
// R6 theory: R5's nontemporal W loads forfeit v2->v3 reuse. W (256 MB) ==
// L3 capacity; forward-forward streaming is LRU-pathological, but
// forward-then-REVERSED within-slab order is LIFO: at v2's end the trailing
// window of every co-resident block's slab is L3-resident, and v3 consumes
// slab tails first => large L3 hit fraction on the second full pass.
//   - W loads: cached (not nt). v1's 32 MB also re-hits at v2's start.
//   - v3 pass: compile-time reversed i/k iteration (template<REV>).
//   - P partials are now the only pollutant => nt stores (gemv_slab) and
//     nt loads (reduce_cols) keep them out of L3.
//   - 16 rows/block (512 blocks) halves P traffic to 16 MB/pass; still
//     8 waves/CU == ~128 KB loads in flight/CU >> ~10 KB needed for HBM.
// Predicted: our-kernel FETCH ~700 -> ~470 MB/iter, dur 444 -> ~385-405.

namespace {
constexpr int N = 8192;
constexpr int NF4 = N / 4;       // 2048 float4 per row
constexpr int IN_N = 1024;
constexpr int OUT_N = 256;
constexpr int BT = 256;

constexpr int B1 = 256;          // blocks for v1 pass (1024 rows / 4)
constexpr int R1R = IN_N / B1;   // 4 rows/block
constexpr int B2 = 512;          // blocks for full-W passes
constexpr int R2R = N / B2;      // 16 rows/block -> 512 KB contiguous slab

// ws float offsets
constexpr size_t OFF_V1 = 0;
constexpr size_t OFF_V2 = 8192;
constexpr size_t OFF_V3 = 16384;
constexpr size_t OFF_V4 = 24576;             // 256 floats
constexpr size_t OFF_P  = 32768;             // up to B2*N floats = 16 MB

typedef float f4 __attribute__((ext_vector_type(4)));
}

__global__ void zero_vecs(float* __restrict__ ws) {
  int i = blockIdx.x * blockDim.x + threadIdx.x;
  if (i < 3 * N + OUT_N) ws[i] = 0.0f;
}

// Block b: rows [b*ROWS, (b+1)*ROWS) of W -- one contiguous slab, streamed
// with 8 independent CACHED float4 loads per row per thread. REV reverses
// the within-slab temporal order (i and k loops) so a pass can consume the
// previous pass's L3-resident slab tails first (LIFO reuse).
// Produces an 8192-wide partial in regs, stored nontemporally to P[b][:]
// (P must not evict W from L3).
template <int ROWS, bool REV>
__global__ __launch_bounds__(BT) void gemv_slab(const float* __restrict__ W,
                                                const float* __restrict__ vin,
                                                float* __restrict__ P) {
  __shared__ float sv[ROWS];
  const int b = blockIdx.x, t = threadIdx.x;
  const int i0 = b * ROWS;
  if (t < ROWS) sv[t] = vin[i0 + t];
  __syncthreads();
  const f4* __restrict__ W4 = reinterpret_cast<const f4*>(W);
  f4 acc[8];
#pragma unroll
  for (int k = 0; k < 8; ++k) acc[k] = (f4)(0.f);
#pragma unroll 2
  for (int ii = 0; ii < ROWS; ++ii) {
    const int i = REV ? (ROWS - 1 - ii) : ii;
    const float s = sv[i];
    const f4* __restrict__ row = W4 + (size_t)(i0 + i) * NF4;
#pragma unroll
    for (int kk = 0; kk < 8; ++kk) {
      const int k = REV ? (7 - kk) : kk;
      const f4 w = row[k * BT + t];
      acc[k] += w * s;
    }
  }
  f4* __restrict__ P4 = reinterpret_cast<f4*>(P) + (size_t)b * NF4;
#pragma unroll
  for (int k = 0; k < 8; ++k)
    __builtin_nontemporal_store(acc[k], P4 + k * BT + t);
}

// v[j] += sum_{c in [c0,c0+CS)} P[c][j]; coalesced 1KB/wave nt reads
// (P is dead after this -- keep it out of L3), one atomicAdd per j per block.
template <int CS>
__global__ __launch_bounds__(BT) void reduce_cols(const float* __restrict__ P,
                                                  float* __restrict__ v) {
  const int j = blockIdx.x * BT + threadIdx.x;
  const int c0 = blockIdx.y * CS;
  float a = 0.f;
#pragma unroll 8
  for (int c = 0; c < CS; ++c)
    a += __builtin_nontemporal_load(P + (size_t)(c0 + c) * N + j);
  atomicAdd(v + j, a);
}

// v4 = (W^T v3) restricted to the last 256 columns (float4 idx 1984..2047).
// Cached loads: after the reversed v3 pass, part of the strip is L3-hot.
__global__ __launch_bounds__(64) void gemv_tail(const float* __restrict__ W,
                                                const float* __restrict__ v3,
                                                float* __restrict__ v4) {
  __shared__ float sv[32];
  const int b = blockIdx.x, t = threadIdx.x;
  const int i0 = b * 32;
  if (t < 32) sv[t] = v3[i0 + t];
  __syncthreads();
  const f4* __restrict__ W4 = reinterpret_cast<const f4*>(W);
  f4 a = (f4)(0.f);
#pragma unroll 4
  for (int i = 0; i < 32; ++i) {
    const f4 w = W4[(size_t)(i0 + i) * NF4 + 1984 + t];
    a += w * sv[i];
  }
  atomicAdd(v4 + 4 * t + 0, a.x);
  atomicAdd(v4 + 4 * t + 1, a.y);
  atomicAdd(v4 + 4 * t + 2, a.z);
  atomicAdd(v4 + 4 * t + 3, a.w);
}

__global__ void diag_scale(const float* __restrict__ W,
                           const float* __restrict__ v4,
                           float* __restrict__ out) {
  const int t = threadIdx.x;
  const size_t j = (size_t)(N - OUT_N + t);
  out[t] = W[j * (N + 1)] * v4[t];
}

extern "C" void kernel_launch(void* const* d_in, const int* in_sizes, int n_in,
                              void* d_out, int out_size, void* d_ws, size_t ws_size,
                              hipStream_t stream) {
  const float* x = (const float*)d_in[0];   // [1,1024] f32
  const float* W = (const float*)d_in[1];   // [8192,8192] f32 row-major
  // d_in[2] = num_steps == 4 (chain hardcoded)
  float* ws = (float*)d_ws;
  float* v1 = ws + OFF_V1;
  float* v2 = ws + OFF_V2;
  float* v3 = ws + OFF_V3;
  float* v4 = ws + OFF_V4;
  float* P  = ws + OFF_P;
  float* out = (float*)d_out;

  zero_vecs<<<(3 * N + OUT_N + 255) / 256, 256, 0, stream>>>(ws);

  // v1 = W[0:1024,:]^T x : 256 slabs x 4 rows (32 MB, warms L3), reduce 8 MB
  gemv_slab<R1R, false><<<B1, BT, 0, stream>>>(W, x, P);
  reduce_cols<32><<<dim3(N / BT, B1 / 32), BT, 0, stream>>>(P, v1);

  // v2 = W^T v1 : 512 slabs x 16 rows, FORWARD (fills L3 with slab tails)
  gemv_slab<R2R, false><<<B2, BT, 0, stream>>>(W, v1, P);
  reduce_cols<32><<<dim3(N / BT, B2 / 32), BT, 0, stream>>>(P, v2);

  // v3 = W^T v2 : same slabs, REVERSED within-slab order (LIFO L3 reuse)
  gemv_slab<R2R, true><<<B2, BT, 0, stream>>>(W, v2, P);
  reduce_cols<32><<<dim3(N / BT, B2 / 32), BT, 0, stream>>>(P, v3);

  // v4 = (W^T v3)[last 256 cols] : 8 MB strip
  gemv_tail<<<N / 32, 64, 0, stream>>>(W, v3, v4);

  // out[t] = W[j,j] * v4[t]
  diag_scale<<<1, OUT_N, 0, stream>>>(W, v4, out);
}

// Round 2
// 435.363 us; speedup vs baseline: 1.0442x; 1.0442x over previous
//
#include <hip/hip_runtime.h>

// AdjacencyMatrix == 4 chained GEMVs with W^T + diagonal scale:
//   v1 = W[0:1024,:]^T x ; v2 = W^T v1 ; v3 = W^T v2 ;
//   v4[last256] = (W^T v3)[last256] ; out[t] = W[j,j]*v4[j], j=7936+t.
//
// Cross-round model: dur_us = kernels + ~265 us FIXED harness overhead
// (1 GiB ws poison fill ~157us @6.8TB/s + 256 MiB W restore ~85us + launch).
// R5 (all-nt, full-width 8-row slabs): 444.5 us  <- prior best
// R6 (cached W + LIFO reversal + nt P): 454.6 us <- L3 reuse theory REFUTED.
//   W (256 MB == L3 size) retains nothing across passes; W must stream nt.
//
// R7: keep R5's nt-W streaming, attack P traffic via 2D tiling.
//   Blocks own (128 rows x 1024 cols) tiles instead of (rows x 8192):
//   same W bytes/block (512 KB, coalesced, nt), but per-block partial is
//   4 KB not 32 KB -> P per full pass = 64 slabs x 32 KB = 2 MB (was 16).
//   P now L2/L3-resident: plain cached stores/loads, reduces are near-free.
//   P round-trip per iteration: ~64 MB -> ~8 MB.
// Predicted: dur 454.6 -> ~420-430 (-15..20 vs R5). If neutral vs R5, P was
// off the critical path => slab read ceiling (~4 TB/s) is the real limit.

namespace {
constexpr int N = 8192;
constexpr int NF4 = N / 4;       // 2048 float4 per row
constexpr int IN_N = 1024;
constexpr int OUT_N = 256;
constexpr int BT = 256;

constexpr int NCT = 8;           // column tiles (8 x 1024 cols = full row)
constexpr int R1R = 32;          // v1 pass rows/block: 32 slabs x 8 ct = 256 blocks
constexpr int R2R = 128;         // full pass rows/block: 64 slabs x 8 ct = 512 blocks
constexpr int SL1 = IN_N / R1R;  // 32 row-slabs (v1)
constexpr int SL2 = N / R2R;     // 64 row-slabs (v2/v3)

// ws float offsets
constexpr size_t OFF_V1 = 0;
constexpr size_t OFF_V2 = 8192;
constexpr size_t OFF_V3 = 16384;
constexpr size_t OFF_V4 = 24576;             // 256 floats
constexpr size_t OFF_P  = 32768;             // up to SL2*N floats = 2 MB

typedef float f4 __attribute__((ext_vector_type(4)));
}

__global__ void zero_vecs(float* __restrict__ ws) {
  int i = blockIdx.x * blockDim.x + threadIdx.x;
  if (i < 3 * N + OUT_N) ws[i] = 0.0f;
}

// Block b = (rs row-slab, ct col-tile): rows [rs*ROWS, (rs+1)*ROWS),
// f4 cols [ct*256, (ct+1)*256). One f4 per thread per row, coalesced 4 KB
// per block-row, NONTEMPORAL (W is a pure stream, L3-pathological).
// Per-block partial is 256 f4 = 4 KB -> P[rs][ct*1024..] with CACHED
// stores; P (2 MB) stays L2/L3-resident for the reduce.
template <int ROWS>
__global__ __launch_bounds__(BT) void gemv_slab(const float* __restrict__ W,
                                                const float* __restrict__ vin,
                                                float* __restrict__ P) {
  __shared__ float sv[ROWS];
  const int b = blockIdx.x, t = threadIdx.x;
  const int ct = b & (NCT - 1);
  const int rs = b >> 3;
  const int i0 = rs * ROWS;
  for (int i = t; i < ROWS; i += BT) sv[i] = vin[i0 + i];
  __syncthreads();
  const f4* __restrict__ W4 = reinterpret_cast<const f4*>(W);
  const int cf = ct * BT + t;    // f4 column index 0..2047
  f4 acc = (f4)(0.f);
#pragma unroll 8
  for (int i = 0; i < ROWS; ++i) {
    const f4 w = __builtin_nontemporal_load(W4 + (size_t)(i0 + i) * NF4 + cf);
    acc += w * sv[i];
  }
  reinterpret_cast<f4*>(P)[(size_t)rs * NF4 + cf] = acc;
}

// v[j] += sum_{c in [c0,c0+CS)} P[c][j]; P is L2/L3-hot (2 MB), plain loads,
// one atomicAdd per j per block.
template <int CS>
__global__ __launch_bounds__(BT) void reduce_cols(const float* __restrict__ P,
                                                  float* __restrict__ v) {
  const int j = blockIdx.x * BT + threadIdx.x;
  const int c0 = blockIdx.y * CS;
  float a = 0.f;
#pragma unroll
  for (int c = 0; c < CS; ++c) a += P[(size_t)(c0 + c) * N + j];
  atomicAdd(v + j, a);
}

// v4 = (W^T v3) restricted to the last 256 columns (float4 idx 1984..2047).
__global__ __launch_bounds__(64) void gemv_tail(const float* __restrict__ W,
                                                const float* __restrict__ v3,
                                                float* __restrict__ v4) {
  __shared__ float sv[32];
  const int b = blockIdx.x, t = threadIdx.x;
  const int i0 = b * 32;
  if (t < 32) sv[t] = v3[i0 + t];
  __syncthreads();
  const f4* __restrict__ W4 = reinterpret_cast<const f4*>(W);
  f4 a = (f4)(0.f);
#pragma unroll 4
  for (int i = 0; i < 32; ++i) {
    const f4 w = W4[(size_t)(i0 + i) * NF4 + 1984 + t];
    a += w * sv[i];
  }
  atomicAdd(v4 + 4 * t + 0, a.x);
  atomicAdd(v4 + 4 * t + 1, a.y);
  atomicAdd(v4 + 4 * t + 2, a.z);
  atomicAdd(v4 + 4 * t + 3, a.w);
}

__global__ void diag_scale(const float* __restrict__ W,
                           const float* __restrict__ v4,
                           float* __restrict__ out) {
  const int t = threadIdx.x;
  const size_t j = (size_t)(N - OUT_N + t);
  out[t] = W[j * (N + 1)] * v4[t];
}

extern "C" void kernel_launch(void* const* d_in, const int* in_sizes, int n_in,
                              void* d_out, int out_size, void* d_ws, size_t ws_size,
                              hipStream_t stream) {
  const float* x = (const float*)d_in[0];   // [1,1024] f32
  const float* W = (const float*)d_in[1];   // [8192,8192] f32 row-major
  // d_in[2] = num_steps == 4 (chain hardcoded)
  float* ws = (float*)d_ws;
  float* v1 = ws + OFF_V1;
  float* v2 = ws + OFF_V2;
  float* v3 = ws + OFF_V3;
  float* v4 = ws + OFF_V4;
  float* P  = ws + OFF_P;
  float* out = (float*)d_out;

  zero_vecs<<<(3 * N + OUT_N + 255) / 256, 256, 0, stream>>>(ws);

  // v1 = W[0:1024,:]^T x : 32 slabs x 8 ct = 256 blocks (32 MB), P = 1 MB
  gemv_slab<R1R><<<SL1 * NCT, BT, 0, stream>>>(W, x, P);
  reduce_cols<16><<<dim3(N / BT, SL1 / 16), BT, 0, stream>>>(P, v1);

  // v2 = W^T v1 : 64 slabs x 8 ct = 512 blocks (256 MB), P = 2 MB
  gemv_slab<R2R><<<SL2 * NCT, BT, 0, stream>>>(W, v1, P);
  reduce_cols<16><<<dim3(N / BT, SL2 / 16), BT, 0, stream>>>(P, v2);

  // v3 = W^T v2
  gemv_slab<R2R><<<SL2 * NCT, BT, 0, stream>>>(W, v2, P);
  reduce_cols<16><<<dim3(N / BT, SL2 / 16), BT, 0, stream>>>(P, v3);

  // v4 = (W^T v3)[last 256 cols] : 8 MB strip
  gemv_tail<<<N / 32, 64, 0, stream>>>(W, v3, v4);

  // out[t] = W[j,j] * v4[t]
  diag_scale<<<1, OUT_N, 0, stream>>>(W, v4, out);
}